// Round 1
// baseline (627.060 us; speedup 1.0000x reference)
//
#include <hip/hip_runtime.h>
#include <hip/hip_bf16.h>

#define NN 50000
#define FD 128

// ---------------- histogram of dst ----------------
__global__ void k_hist(const int* __restrict__ dst, int* __restrict__ cnt, int e) {
    int i = blockIdx.x * blockDim.x + threadIdx.x;
    if (i < e) atomicAdd(&cnt[dst[i]], 1);
}

// ---------------- single-block exclusive scan (wave-shuffle based) ----------------
__global__ void k_scan(const int* __restrict__ cnt, int* __restrict__ rowptr,
                       int* __restrict__ cursor, int n) {
    __shared__ int wsum[16];
    __shared__ int woff[17];
    const int t = threadIdx.x;          // 0..1023
    const int lane = t & 63, wid = t >> 6;
    int carry = 0;
    for (int base = 0; base < n; base += 1024) {
        int idx = base + t;
        int v = (idx < n) ? cnt[idx] : 0;
        int s = v;
#pragma unroll
        for (int off = 1; off < 64; off <<= 1) {
            int u = __shfl_up(s, off, 64);
            if (lane >= off) s += u;
        }
        if (lane == 63) wsum[wid] = s;
        __syncthreads();
        if (wid == 0) {
            int wv = (lane < 16) ? wsum[lane] : 0;
            int w2 = wv;
#pragma unroll
            for (int off = 1; off < 16; off <<= 1) {
                int u = __shfl_up(w2, off, 64);
                if (lane >= off) w2 += u;
            }
            if (lane < 16) woff[lane + 1] = w2;
            if (lane == 0) woff[0] = 0;
        }
        __syncthreads();
        int excl = carry + woff[wid] + (s - v);
        if (idx < n) { rowptr[idx] = excl; cursor[idx] = excl; }
        carry += woff[16];
        __syncthreads();
    }
    if (t == 0) rowptr[n] = carry;
}

// ---------------- scatter edges into CSR ----------------
__global__ void k_scatter(const int* __restrict__ src, const int* __restrict__ dst,
                          int* __restrict__ cursor, int* __restrict__ colidx, int e) {
    int i = blockIdx.x * blockDim.x + threadIdx.x;
    if (i < e) {
        int d = dst[i];
        int pos = atomicAdd(&cursor[d], 1);
        colidx[pos] = src[i];
    }
}

// ---------------- fp32 GEMM: H[n,128] = X[n,128] @ W[128,128] ----------------
#define BM 64
__global__ __launch_bounds__(256) void k_gemm(const float* __restrict__ X,
                                              const float* __restrict__ W,
                                              float* __restrict__ H, int n) {
    __shared__ float sW[128 * 128];     // 64 KB
    __shared__ float sXt[128 * 65];     // 33.3 KB, transposed + padded
    const int t = threadIdx.x;
    const int row0 = blockIdx.x * BM;
#pragma unroll
    for (int i = 0; i < 64; i++) sW[i * 256 + t] = W[i * 256 + t];
#pragma unroll
    for (int i = 0; i < 32; i++) {
        int f = i * 256 + t;
        int r = f >> 7, k = f & 127;
        int rr = row0 + r;
        float v = (rr < n) ? X[(size_t)rr * 128 + k] : 0.f;
        sXt[k * 65 + r] = v;
    }
    __syncthreads();
    const int c0 = (t & 31) * 4;
    const int r0 = (t >> 5) * 8;
    float acc[8][4] = {};
#pragma unroll 4
    for (int k = 0; k < 128; k++) {
        float4 wv = *(const float4*)&sW[k * 128 + c0];
        float4 xa = *(const float4*)&sXt[k * 65 + r0];
        float4 xb = *(const float4*)&sXt[k * 65 + r0 + 4];
        float xr[8] = {xa.x, xa.y, xa.z, xa.w, xb.x, xb.y, xb.z, xb.w};
#pragma unroll
        for (int i = 0; i < 8; i++) {
            acc[i][0] += xr[i] * wv.x;
            acc[i][1] += xr[i] * wv.y;
            acc[i][2] += xr[i] * wv.z;
            acc[i][3] += xr[i] * wv.w;
        }
    }
#pragma unroll
    for (int i = 0; i < 8; i++) {
        int rr = row0 + r0 + i;
        if (rr < n) *(float4*)&H[(size_t)rr * 128 + c0] = *(float4*)&acc[i][0];
    }
}

// ---------------- per-node attention dots: as = h . a_src, ad = h . a_dst ----------------
__global__ void k_dots(const float* __restrict__ H, const float* __restrict__ a_s,
                       const float* __restrict__ a_d, float* __restrict__ as_,
                       float* __restrict__ ad_, int n) {
    int wid = threadIdx.x >> 6, lane = threadIdx.x & 63;
    int node = blockIdx.x * 4 + wid;
    if (node >= n) return;
    float2 hv = *(const float2*)&H[(size_t)node * 128 + lane * 2];
    float2 s2 = *(const float2*)&a_s[lane * 2];
    float2 d2 = *(const float2*)&a_d[lane * 2];
    float v1 = hv.x * s2.x + hv.y * s2.y;
    float v2 = hv.x * d2.x + hv.y * d2.y;
#pragma unroll
    for (int off = 32; off; off >>= 1) {
        v1 += __shfl_xor(v1, off);
        v2 += __shfl_xor(v2, off);
    }
    if (lane == 0) { as_[node] = v1; ad_[node] = v2; }
}

// ---------------- fused softmax + aggregation, one wave per dst node ----------------
__global__ __launch_bounds__(256) void k_aggr(const float* __restrict__ H,
                                              const float* __restrict__ as_,
                                              const float* __restrict__ ad_,
                                              const int* __restrict__ rowptr,
                                              const int* __restrict__ colidx,
                                              const float* __restrict__ bias,
                                              float* __restrict__ out, int n, int do_relu) {
    const int wid = threadIdx.x >> 6;
    const int lane = threadIdx.x & 63;
    const int node = blockIdx.x * 4 + wid;
    if (node >= n) return;
    const int half = lane >> 5;     // two edges in flight per wave
    const int l = lane & 31;
    const int c0 = l * 4;
    const float adn = ad_[node];
    float s_acc = 0.f;
    float4 acc = {0.f, 0.f, 0.f, 0.f};
    const int beg = rowptr[node], end = rowptr[node + 1];
    for (int i = beg + half; i < end; i += 2) {
        const int srcn = colidx[i];
        float e = as_[srcn] + adn;
        e = (e > 0.f) ? e : 0.2f * e;
        const float w = __expf(e);
        const float4 hv = *(const float4*)&H[(size_t)srcn * 128 + c0];
        s_acc += w;
        acc.x += w * hv.x; acc.y += w * hv.y; acc.z += w * hv.z; acc.w += w * hv.w;
    }
    if (half == 0) {   // self loop
        float e = as_[node] + adn;
        e = (e > 0.f) ? e : 0.2f * e;
        const float w = __expf(e);
        const float4 hv = *(const float4*)&H[(size_t)node * 128 + c0];
        s_acc += w;
        acc.x += w * hv.x; acc.y += w * hv.y; acc.z += w * hv.z; acc.w += w * hv.w;
    }
    // combine the two halves (lanes i and i+32 hold the same feature strip)
    s_acc += __shfl_xor(s_acc, 32);
    acc.x += __shfl_xor(acc.x, 32);
    acc.y += __shfl_xor(acc.y, 32);
    acc.z += __shfl_xor(acc.z, 32);
    acc.w += __shfl_xor(acc.w, 32);
    if (half == 0) {
        const float inv = 1.f / s_acc;
        const float4 bv = *(const float4*)&bias[c0];
        float4 o;
        o.x = acc.x * inv + bv.x;
        o.y = acc.y * inv + bv.y;
        o.z = acc.z * inv + bv.z;
        o.w = acc.w * inv + bv.w;
        if (do_relu) {
            o.x = fmaxf(o.x, 0.f); o.y = fmaxf(o.y, 0.f);
            o.z = fmaxf(o.z, 0.f); o.w = fmaxf(o.w, 0.f);
        }
        *(float4*)&out[(size_t)node * 128 + c0] = o;
    }
}

extern "C" void kernel_launch(void* const* d_in, const int* in_sizes, int n_in,
                              void* d_out, int out_size, void* d_ws, size_t ws_size,
                              hipStream_t stream) {
    const float* x     = (const float*)d_in[0];
    const int*   ei    = (const int*)d_in[1];
    const float* W1    = (const float*)d_in[2];
    const float* a1s   = (const float*)d_in[3];
    const float* a1d   = (const float*)d_in[4];
    const float* b1    = (const float*)d_in[5];
    const float* W2    = (const float*)d_in[6];
    const float* a2s   = (const float*)d_in[7];
    const float* a2d   = (const float*)d_in[8];
    const float* b2    = (const float*)d_in[9];
    float* dout = (float*)d_out;

    const int n = in_sizes[0] / FD;          // 50000
    const int E = in_sizes[1] / 2;           // 1600000
    const int* src = ei;
    const int* dst = ei + E;

    // workspace layout
    float* A      = (float*)d_ws;            // n*128 floats (h buffer)
    float* as_    = A + (size_t)n * FD;      // n
    float* ad_    = as_ + n;                 // n
    int*   rowptr = (int*)(ad_ + n);         // n+1
    int*   cursor = rowptr + (n + 1);        // n
    int*   colidx = cursor + n;              // E

    // ---- CSR build (shared by both layers) ----
    hipMemsetAsync(cursor, 0, (size_t)n * sizeof(int), stream);
    k_hist<<<(E + 255) / 256, 256, 0, stream>>>(dst, cursor, E);
    k_scan<<<1, 1024, 0, stream>>>(cursor, rowptr, cursor, n);
    k_scatter<<<(E + 255) / 256, 256, 0, stream>>>(src, dst, cursor, colidx, E);

    const int gemm_grid = (n + BM - 1) / BM;
    const int node_grid = (n + 3) / 4;

    // ---- layer 1: h1 = x@W1 -> aggregate -> relu -> d_out ----
    k_gemm<<<gemm_grid, 256, 0, stream>>>(x, W1, A, n);
    k_dots<<<node_grid, 256, 0, stream>>>(A, a1s, a1d, as_, ad_, n);
    k_aggr<<<node_grid, 256, 0, stream>>>(A, as_, ad_, rowptr, colidx, b1, dout, n, 1);

    // ---- layer 2: h2 = out1@W2 -> aggregate -> d_out ----
    k_gemm<<<gemm_grid, 256, 0, stream>>>(dout, W2, A, n);
    k_dots<<<node_grid, 256, 0, stream>>>(A, a2s, a2d, as_, ad_, n);
    k_aggr<<<node_grid, 256, 0, stream>>>(A, as_, ad_, rowptr, colidx, b2, dout, n, 0);
}

// Round 2
// 451.067 us; speedup vs baseline: 1.3902x; 1.3902x over previous
//
#include <hip/hip_runtime.h>
#include <hip/hip_bf16.h>

#define FD 128
#define CBW 64            // coarse bucket width: bucket = dst >> 6
#define NB_MAX 1024

// ---------------- coarse histogram (LDS-aggregated) ----------------
__global__ __launch_bounds__(256) void k_chist(const int* __restrict__ dst,
                                               int* __restrict__ ccnt, int e, int nb) {
    __shared__ int lh[NB_MAX];
    for (int i = threadIdx.x; i < nb; i += 256) lh[i] = 0;
    __syncthreads();
    for (int i = blockIdx.x * 256 + threadIdx.x; i < e; i += gridDim.x * 256)
        atomicAdd(&lh[dst[i] >> 6], 1);
    __syncthreads();
    for (int i = threadIdx.x; i < nb; i += 256) {
        int c = lh[i];
        if (c) atomicAdd(&ccnt[i], c);
    }
}

// ---------------- scan of coarse counts (single block) ----------------
__global__ void k_cscan(const int* __restrict__ ccnt, int* __restrict__ cbase,
                        int* __restrict__ ccur, int nb, int* __restrict__ rowptr, int n) {
    __shared__ int wsum[16];
    __shared__ int woff[17];
    const int t = threadIdx.x, lane = t & 63, wid = t >> 6;
    int carry = 0;
    for (int base = 0; base < nb; base += 1024) {
        int idx = base + t;
        int v = (idx < nb) ? ccnt[idx] : 0;
        int s = v;
#pragma unroll
        for (int off = 1; off < 64; off <<= 1) {
            int u = __shfl_up(s, off, 64);
            if (lane >= off) s += u;
        }
        if (lane == 63) wsum[wid] = s;
        __syncthreads();
        if (wid == 0) {
            int w2 = (lane < 16) ? wsum[lane] : 0;
#pragma unroll
            for (int off = 1; off < 16; off <<= 1) {
                int u = __shfl_up(w2, off, 64);
                if (lane >= off) w2 += u;
            }
            if (lane < 16) woff[lane + 1] = w2;
            if (lane == 0) woff[0] = 0;
        }
        __syncthreads();
        int excl = carry + woff[wid] + (s - v);
        if (idx < nb) { cbase[idx] = excl; ccur[idx] = excl; }
        carry += woff[16];
        __syncthreads();
    }
    if (t == 0) { cbase[nb] = carry; rowptr[n] = carry; }
}

// ---------------- coarse scatter: pack (src<<6 | dst&63) into bucket-major ebuf ----------------
__global__ __launch_bounds__(256) void k_cscatter(const int* __restrict__ src,
                                                  const int* __restrict__ dst,
                                                  int* __restrict__ ccur,
                                                  int* __restrict__ ebuf,
                                                  int e, int nb, int nblocks) {
    __shared__ int lh[NB_MAX];
    __shared__ int lb[NB_MAX];
    const int per = (e + nblocks - 1) / nblocks;
    const int lo = blockIdx.x * per;
    const int hi = min(e, lo + per);
    const int t = threadIdx.x;
    for (int i = t; i < nb; i += 256) lh[i] = 0;
    __syncthreads();
    for (int i = lo + t; i < hi; i += 256) atomicAdd(&lh[dst[i] >> 6], 1);
    __syncthreads();
    for (int i = t; i < nb; i += 256) {
        int c = lh[i];
        lb[i] = c ? atomicAdd(&ccur[i], c) : 0;
    }
    __syncthreads();
    for (int i = t; i < nb; i += 256) lh[i] = 0;
    __syncthreads();
    for (int i = lo + t; i < hi; i += 256) {
        int d = dst[i];
        int bkt = d >> 6;
        int r = atomicAdd(&lh[bkt], 1);
        ebuf[lb[bkt] + r] = (src[i] << 6) | (d & (CBW - 1));
    }
}

// ---------------- fine counting sort within each coarse bucket ----------------
__global__ __launch_bounds__(256) void k_fine(const int* __restrict__ ebuf,
                                              const int* __restrict__ cbase,
                                              int* __restrict__ rowptr,
                                              int* __restrict__ colidx, int n) {
    const int b = blockIdx.x;
    const int node0 = b * CBW;
    const int nloc = min(CBW, n - node0);
    const int beg = cbase[b], end = cbase[b + 1];
    __shared__ int fh[CBW];
    __shared__ int fo[CBW];
    const int t = threadIdx.x;
    if (t < CBW) fh[t] = 0;
    __syncthreads();
    for (int e = beg + t; e < end; e += 256) atomicAdd(&fh[ebuf[e] & (CBW - 1)], 1);
    __syncthreads();
    if (t < 64) {                       // wave 0: exclusive scan of 64 counts
        int v = fh[t];
        int s = v;
#pragma unroll
        for (int off = 1; off < 64; off <<= 1) {
            int u = __shfl_up(s, off, 64);
            if (t >= off) s += u;
        }
        fo[t] = s - v;
    }
    __syncthreads();
    if (t < nloc) rowptr[node0 + t] = beg + fo[t];
    if (t < CBW) fh[t] = 0;
    __syncthreads();
    for (int e = beg + t; e < end; e += 256) {
        int v = ebuf[e];
        int d = v & (CBW - 1);
        int r = atomicAdd(&fh[d], 1);
        colidx[beg + fo[d] + r] = v >> 6;
    }
}

// ---------------- fp32 GEMM + fused attention dots ----------------
#define BM 64
__global__ __launch_bounds__(256) void k_gemm(const float* __restrict__ X,
                                              const float* __restrict__ W,
                                              const float* __restrict__ a_s,
                                              const float* __restrict__ a_d,
                                              float* __restrict__ H,
                                              float* __restrict__ as_,
                                              float* __restrict__ ad_, int n) {
    __shared__ float sW[128 * 128];     // 64 KB
    __shared__ float sXt[128 * 65];     // 33.3 KB, transposed + padded
    const int t = threadIdx.x;
    const int row0 = blockIdx.x * BM;
#pragma unroll
    for (int i = 0; i < 64; i++) sW[i * 256 + t] = W[i * 256 + t];
#pragma unroll
    for (int i = 0; i < 32; i++) {
        int f = i * 256 + t;
        int r = f >> 7, k = f & 127;
        int rr = row0 + r;
        float v = (rr < n) ? X[(size_t)rr * 128 + k] : 0.f;
        sXt[k * 65 + r] = v;
    }
    __syncthreads();
    const int c0 = (t & 31) * 4;
    const int r0 = (t >> 5) * 8;
    float acc[8][4] = {};
#pragma unroll 4
    for (int k = 0; k < 128; k++) {
        float4 wv = *(const float4*)&sW[k * 128 + c0];
        float4 xa = *(const float4*)&sXt[k * 65 + r0];
        float4 xb = *(const float4*)&sXt[k * 65 + r0 + 4];
        float xr[8] = {xa.x, xa.y, xa.z, xa.w, xb.x, xb.y, xb.z, xb.w};
#pragma unroll
        for (int i = 0; i < 8; i++) {
            acc[i][0] += xr[i] * wv.x;
            acc[i][1] += xr[i] * wv.y;
            acc[i][2] += xr[i] * wv.z;
            acc[i][3] += xr[i] * wv.w;
        }
    }
    const float4 asv = *(const float4*)&a_s[c0];
    const float4 adv = *(const float4*)&a_d[c0];
#pragma unroll
    for (int i = 0; i < 8; i++) {
        int rr = row0 + r0 + i;
        if (rr < n) *(float4*)&H[(size_t)rr * 128 + c0] = *(float4*)&acc[i][0];
        float vs = acc[i][0] * asv.x + acc[i][1] * asv.y + acc[i][2] * asv.z + acc[i][3] * asv.w;
        float vd = acc[i][0] * adv.x + acc[i][1] * adv.y + acc[i][2] * adv.z + acc[i][3] * adv.w;
#pragma unroll
        for (int off = 16; off; off >>= 1) {
            vs += __shfl_xor(vs, off, 32);
            vd += __shfl_xor(vd, off, 32);
        }
        if ((t & 31) == 0 && rr < n) { as_[rr] = vs; ad_[rr] = vd; }
    }
}

// ---------------- fused softmax + aggregation, one wave per dst node ----------------
__global__ __launch_bounds__(256) void k_aggr(const float* __restrict__ H,
                                              const float* __restrict__ as_,
                                              const float* __restrict__ ad_,
                                              const int* __restrict__ rowptr,
                                              const int* __restrict__ colidx,
                                              const float* __restrict__ bias,
                                              float* __restrict__ out, int n, int do_relu) {
    const int wid = threadIdx.x >> 6;
    const int lane = threadIdx.x & 63;
    const int node = blockIdx.x * 4 + wid;
    if (node >= n) return;
    const int half = lane >> 5;     // two edges in flight per wave
    const int l = lane & 31;
    const int c0 = l * 4;
    const float adn = ad_[node];
    float s_acc = 0.f;
    float4 acc = {0.f, 0.f, 0.f, 0.f};
    const int beg = rowptr[node], end = rowptr[node + 1];
    for (int i = beg + half; i < end; i += 2) {
        const int srcn = colidx[i];
        float e = as_[srcn] + adn;
        e = (e > 0.f) ? e : 0.2f * e;
        const float w = __expf(e);
        const float4 hv = *(const float4*)&H[(size_t)srcn * 128 + c0];
        s_acc += w;
        acc.x += w * hv.x; acc.y += w * hv.y; acc.z += w * hv.z; acc.w += w * hv.w;
    }
    if (half == 0) {   // self loop
        float e = as_[node] + adn;
        e = (e > 0.f) ? e : 0.2f * e;
        const float w = __expf(e);
        const float4 hv = *(const float4*)&H[(size_t)node * 128 + c0];
        s_acc += w;
        acc.x += w * hv.x; acc.y += w * hv.y; acc.z += w * hv.z; acc.w += w * hv.w;
    }
    s_acc += __shfl_xor(s_acc, 32);
    acc.x += __shfl_xor(acc.x, 32);
    acc.y += __shfl_xor(acc.y, 32);
    acc.z += __shfl_xor(acc.z, 32);
    acc.w += __shfl_xor(acc.w, 32);
    if (half == 0) {
        const float inv = 1.f / s_acc;
        const float4 bv = *(const float4*)&bias[c0];
        float4 o;
        o.x = acc.x * inv + bv.x;
        o.y = acc.y * inv + bv.y;
        o.z = acc.z * inv + bv.z;
        o.w = acc.w * inv + bv.w;
        if (do_relu) {
            o.x = fmaxf(o.x, 0.f); o.y = fmaxf(o.y, 0.f);
            o.z = fmaxf(o.z, 0.f); o.w = fmaxf(o.w, 0.f);
        }
        *(float4*)&out[(size_t)node * 128 + c0] = o;
    }
}

extern "C" void kernel_launch(void* const* d_in, const int* in_sizes, int n_in,
                              void* d_out, int out_size, void* d_ws, size_t ws_size,
                              hipStream_t stream) {
    const float* x   = (const float*)d_in[0];
    const int*   ei  = (const int*)d_in[1];
    const float* W1  = (const float*)d_in[2];
    const float* a1s = (const float*)d_in[3];
    const float* a1d = (const float*)d_in[4];
    const float* b1  = (const float*)d_in[5];
    const float* W2  = (const float*)d_in[6];
    const float* a2s = (const float*)d_in[7];
    const float* a2d = (const float*)d_in[8];
    const float* b2  = (const float*)d_in[9];
    float* dout = (float*)d_out;

    const int n = in_sizes[0] / FD;          // 50000
    const int E = in_sizes[1] / 2;           // 1600000
    const int* src = ei;
    const int* dst = ei + E;
    const int NB = (n + CBW - 1) / CBW;      // 782 coarse buckets

    // workspace layout (ebuf aliases A: A is dead during CSR build)
    float* A      = (float*)d_ws;            // n*128 floats (h buffer)
    int*   ebuf   = (int*)d_ws;              // E ints, bucket-major packed edges
    float* as_    = A + (size_t)n * FD;      // n
    float* ad_    = as_ + n;                 // n
    int*   rowptr = (int*)(ad_ + n);         // n+1
    int*   ccnt   = rowptr + (n + 1);        // NB
    int*   cbase  = ccnt + NB;               // NB+1
    int*   ccur   = cbase + NB + 1;          // NB
    int*   colidx = ccur + NB;               // E

    // ---- CSR build (shared by both layers) ----
    hipMemsetAsync(ccnt, 0, (size_t)NB * sizeof(int), stream);
    k_chist<<<256, 256, 0, stream>>>(dst, ccnt, E, NB);
    k_cscan<<<1, 1024, 0, stream>>>(ccnt, cbase, ccur, NB, rowptr, n);
    const int SCAT_BLOCKS = 256;
    k_cscatter<<<SCAT_BLOCKS, 256, 0, stream>>>(src, dst, ccur, ebuf, E, NB, SCAT_BLOCKS);
    k_fine<<<NB, 256, 0, stream>>>(ebuf, cbase, rowptr, colidx, n);

    const int gemm_grid = (n + BM - 1) / BM;
    const int node_grid = (n + 3) / 4;

    // ---- layer 1: h1 = x@W1 (+dots) -> aggregate -> relu -> d_out ----
    k_gemm<<<gemm_grid, 256, 0, stream>>>(x, W1, a1s, a1d, A, as_, ad_, n);
    k_aggr<<<node_grid, 256, 0, stream>>>(A, as_, ad_, rowptr, colidx, b1, dout, n, 1);

    // ---- layer 2: h2 = out1@W2 (+dots) -> aggregate -> d_out ----
    k_gemm<<<gemm_grid, 256, 0, stream>>>(dout, W2, a2s, a2d, A, as_, ad_, n);
    k_aggr<<<node_grid, 256, 0, stream>>>(A, as_, ad_, rowptr, colidx, b2, dout, n, 0);
}

// Round 3
// 357.627 us; speedup vs baseline: 1.7534x; 1.2613x over previous
//
#include <hip/hip_runtime.h>
#include <hip/hip_bf16.h>
#include <hip/hip_fp16.h>

#define FD 128
#define CBW 64            // coarse bucket width: bucket = dst >> 6
#define NB_MAX 1024

// ---------------- coarse histogram (LDS-aggregated) ----------------
__global__ __launch_bounds__(256) void k_chist(const int* __restrict__ dst,
                                               int* __restrict__ ccnt, int e, int nb) {
    __shared__ int lh[NB_MAX];
    for (int i = threadIdx.x; i < nb; i += 256) lh[i] = 0;
    __syncthreads();
    for (int i = blockIdx.x * 256 + threadIdx.x; i < e; i += gridDim.x * 256)
        atomicAdd(&lh[dst[i] >> 6], 1);
    __syncthreads();
    for (int i = threadIdx.x; i < nb; i += 256) {
        int c = lh[i];
        if (c) atomicAdd(&ccnt[i], c);
    }
}

// ---------------- scan of coarse counts (single block) ----------------
__global__ void k_cscan(const int* __restrict__ ccnt, int* __restrict__ cbase,
                        int* __restrict__ ccur, int nb, int* __restrict__ rowptr, int n) {
    __shared__ int wsum[16];
    __shared__ int woff[17];
    const int t = threadIdx.x, lane = t & 63, wid = t >> 6;
    int carry = 0;
    for (int base = 0; base < nb; base += 1024) {
        int idx = base + t;
        int v = (idx < nb) ? ccnt[idx] : 0;
        int s = v;
#pragma unroll
        for (int off = 1; off < 64; off <<= 1) {
            int u = __shfl_up(s, off, 64);
            if (lane >= off) s += u;
        }
        if (lane == 63) wsum[wid] = s;
        __syncthreads();
        if (wid == 0) {
            int w2 = (lane < 16) ? wsum[lane] : 0;
#pragma unroll
            for (int off = 1; off < 16; off <<= 1) {
                int u = __shfl_up(w2, off, 64);
                if (lane >= off) w2 += u;
            }
            if (lane < 16) woff[lane + 1] = w2;
            if (lane == 0) woff[0] = 0;
        }
        __syncthreads();
        int excl = carry + woff[wid] + (s - v);
        if (idx < nb) { cbase[idx] = excl; ccur[idx] = excl; }
        carry += woff[16];
        __syncthreads();
    }
    if (t == 0) { cbase[nb] = carry; rowptr[n] = carry; }
}

// ---------------- coarse scatter: pack (src<<6 | dst&63) into bucket-major ebuf ----------------
__global__ __launch_bounds__(256) void k_cscatter(const int* __restrict__ src,
                                                  const int* __restrict__ dst,
                                                  int* __restrict__ ccur,
                                                  int* __restrict__ ebuf,
                                                  int e, int nb, int nblocks) {
    __shared__ int lh[NB_MAX];
    __shared__ int lb[NB_MAX];
    const int per = (e + nblocks - 1) / nblocks;
    const int lo = blockIdx.x * per;
    const int hi = min(e, lo + per);
    const int t = threadIdx.x;
    for (int i = t; i < nb; i += 256) lh[i] = 0;
    __syncthreads();
    for (int i = lo + t; i < hi; i += 256) atomicAdd(&lh[dst[i] >> 6], 1);
    __syncthreads();
    for (int i = t; i < nb; i += 256) {
        int c = lh[i];
        lb[i] = c ? atomicAdd(&ccur[i], c) : 0;
    }
    __syncthreads();
    for (int i = t; i < nb; i += 256) lh[i] = 0;
    __syncthreads();
    for (int i = lo + t; i < hi; i += 256) {
        int d = dst[i];
        int bkt = d >> 6;
        int r = atomicAdd(&lh[bkt], 1);
        ebuf[lb[bkt] + r] = (src[i] << 6) | (d & (CBW - 1));
    }
}

// ---------------- fine counting sort within each coarse bucket ----------------
__global__ __launch_bounds__(256) void k_fine(const int* __restrict__ ebuf,
                                              const int* __restrict__ cbase,
                                              int* __restrict__ rowptr,
                                              int* __restrict__ colidx, int n) {
    const int b = blockIdx.x;
    const int node0 = b * CBW;
    const int nloc = min(CBW, n - node0);
    const int beg = cbase[b], end = cbase[b + 1];
    __shared__ int fh[CBW];
    __shared__ int fo[CBW];
    const int t = threadIdx.x;
    if (t < CBW) fh[t] = 0;
    __syncthreads();
    for (int e = beg + t; e < end; e += 256) atomicAdd(&fh[ebuf[e] & (CBW - 1)], 1);
    __syncthreads();
    if (t < 64) {                       // wave 0: exclusive scan of 64 counts
        int v = fh[t];
        int s = v;
#pragma unroll
        for (int off = 1; off < 64; off <<= 1) {
            int u = __shfl_up(s, off, 64);
            if (t >= off) s += u;
        }
        fo[t] = s - v;
    }
    __syncthreads();
    if (t < nloc) rowptr[node0 + t] = beg + fo[t];
    if (t < CBW) fh[t] = 0;
    __syncthreads();
    for (int e = beg + t; e < end; e += 256) {
        int v = ebuf[e];
        int d = v & (CBW - 1);
        int r = atomicAdd(&fh[d], 1);
        colidx[beg + fo[d] + r] = v >> 6;
    }
}

// ---------------- fp32 GEMM + fused attention dots; H written in fp16 ----------------
#define BM 64
__global__ __launch_bounds__(256) void k_gemm(const float* __restrict__ X,
                                              const float* __restrict__ W,
                                              const float* __restrict__ a_s,
                                              const float* __restrict__ a_d,
                                              __half* __restrict__ H,
                                              float* __restrict__ as_,
                                              float* __restrict__ ad_, int n) {
    __shared__ float sW[128 * 128];     // 64 KB
    __shared__ float sXt[128 * 65];     // 33.3 KB, transposed + padded
    const int t = threadIdx.x;
    const int row0 = blockIdx.x * BM;
#pragma unroll
    for (int i = 0; i < 64; i++) sW[i * 256 + t] = W[i * 256 + t];
#pragma unroll
    for (int i = 0; i < 32; i++) {
        int f = i * 256 + t;
        int r = f >> 7, k = f & 127;
        int rr = row0 + r;
        float v = (rr < n) ? X[(size_t)rr * 128 + k] : 0.f;
        sXt[k * 65 + r] = v;
    }
    __syncthreads();
    const int c0 = (t & 31) * 4;
    const int r0 = (t >> 5) * 8;
    float acc[8][4] = {};
#pragma unroll 4
    for (int k = 0; k < 128; k++) {
        float4 wv = *(const float4*)&sW[k * 128 + c0];
        float4 xa = *(const float4*)&sXt[k * 65 + r0];
        float4 xb = *(const float4*)&sXt[k * 65 + r0 + 4];
        float xr[8] = {xa.x, xa.y, xa.z, xa.w, xb.x, xb.y, xb.z, xb.w};
#pragma unroll
        for (int i = 0; i < 8; i++) {
            acc[i][0] += xr[i] * wv.x;
            acc[i][1] += xr[i] * wv.y;
            acc[i][2] += xr[i] * wv.z;
            acc[i][3] += xr[i] * wv.w;
        }
    }
    const float4 asv = *(const float4*)&a_s[c0];
    const float4 adv = *(const float4*)&a_d[c0];
#pragma unroll
    for (int i = 0; i < 8; i++) {
        int rr = row0 + r0 + i;
        if (rr < n) {
            union { __half2 h2[2]; uint2 u; } pk;
            pk.h2[0] = __floats2half2_rn(acc[i][0], acc[i][1]);
            pk.h2[1] = __floats2half2_rn(acc[i][2], acc[i][3]);
            *(uint2*)&H[(size_t)rr * 128 + c0] = pk.u;
        }
        float vs = acc[i][0] * asv.x + acc[i][1] * asv.y + acc[i][2] * asv.z + acc[i][3] * asv.w;
        float vd = acc[i][0] * adv.x + acc[i][1] * adv.y + acc[i][2] * adv.z + acc[i][3] * adv.w;
#pragma unroll
        for (int off = 16; off; off >>= 1) {
            vs += __shfl_xor(vs, off, 32);
            vd += __shfl_xor(vd, off, 32);
        }
        if ((t & 31) == 0 && rr < n) { as_[rr] = vs; ad_[rr] = vd; }
    }
}

// ---------------- fused softmax + aggregation: 1 wave/node, 4 edges in flight ----------------
__global__ __launch_bounds__(256) void k_aggr(const __half* __restrict__ H,
                                              const float* __restrict__ as_,
                                              const float* __restrict__ ad_,
                                              const int* __restrict__ rowptr,
                                              const int* __restrict__ colidx,
                                              const float* __restrict__ bias,
                                              float* __restrict__ out, int n, int do_relu) {
    const int wid = threadIdx.x >> 6;
    const int lane = threadIdx.x & 63;
    const int node = blockIdx.x * 4 + wid;
    if (node >= n) return;
    const int q = lane >> 4;          // quarter-wave: 4 edges in flight
    const int l = lane & 15;
    const int f0 = l * 8;             // 8 fp16 features per lane
    const float adn = ad_[node];
    float s_acc = 0.f;
    float a0 = 0.f, a1 = 0.f, a2 = 0.f, a3 = 0.f, a4 = 0.f, a5 = 0.f, a6 = 0.f, a7 = 0.f;
    const int beg = rowptr[node], end = rowptr[node + 1];
    int i = beg + q;
    int src_n = 0; float as_n = 0.f;
    if (i < end) { src_n = colidx[i]; as_n = as_[src_n]; }
    while (i < end) {
        const int src_c = src_n; const float as_c = as_n;
        const uint4 hv = *(const uint4*)&H[(size_t)src_c * 128 + f0];   // 8 halves
        const int i2 = i + 4;
        if (i2 < end) { src_n = colidx[i2]; as_n = as_[src_n]; }        // prefetch chain
        float e = as_c + adn;
        e = (e > 0.f) ? e : 0.2f * e;
        const float w = __expf(e);
        s_acc += w;
        float2 p;
        p = __half22float2(*(const __half2*)&hv.x); a0 += w * p.x; a1 += w * p.y;
        p = __half22float2(*(const __half2*)&hv.y); a2 += w * p.x; a3 += w * p.y;
        p = __half22float2(*(const __half2*)&hv.z); a4 += w * p.x; a5 += w * p.y;
        p = __half22float2(*(const __half2*)&hv.w); a6 += w * p.x; a7 += w * p.y;
        i = i2;
    }
    if (q == 3) {   // self loop
        float e = as_[node] + adn;
        e = (e > 0.f) ? e : 0.2f * e;
        const float w = __expf(e);
        s_acc += w;
        const uint4 hv = *(const uint4*)&H[(size_t)node * 128 + f0];
        float2 p;
        p = __half22float2(*(const __half2*)&hv.x); a0 += w * p.x; a1 += w * p.y;
        p = __half22float2(*(const __half2*)&hv.y); a2 += w * p.x; a3 += w * p.y;
        p = __half22float2(*(const __half2*)&hv.z); a4 += w * p.x; a5 += w * p.y;
        p = __half22float2(*(const __half2*)&hv.w); a6 += w * p.x; a7 += w * p.y;
    }
    // combine quarters (lanes l, l+16, l+32, l+48 hold the same features)
#pragma unroll
    for (int off = 16; off <= 32; off <<= 1) {
        s_acc += __shfl_xor(s_acc, off);
        a0 += __shfl_xor(a0, off); a1 += __shfl_xor(a1, off);
        a2 += __shfl_xor(a2, off); a3 += __shfl_xor(a3, off);
        a4 += __shfl_xor(a4, off); a5 += __shfl_xor(a5, off);
        a6 += __shfl_xor(a6, off); a7 += __shfl_xor(a7, off);
    }
    if (q == 0) {
        const float inv = 1.f / s_acc;
        const float4 b0 = *(const float4*)&bias[f0];
        const float4 b1 = *(const float4*)&bias[f0 + 4];
        float4 o0, o1;
        o0.x = a0 * inv + b0.x; o0.y = a1 * inv + b0.y;
        o0.z = a2 * inv + b0.z; o0.w = a3 * inv + b0.w;
        o1.x = a4 * inv + b1.x; o1.y = a5 * inv + b1.y;
        o1.z = a6 * inv + b1.z; o1.w = a7 * inv + b1.w;
        if (do_relu) {
            o0.x = fmaxf(o0.x, 0.f); o0.y = fmaxf(o0.y, 0.f);
            o0.z = fmaxf(o0.z, 0.f); o0.w = fmaxf(o0.w, 0.f);
            o1.x = fmaxf(o1.x, 0.f); o1.y = fmaxf(o1.y, 0.f);
            o1.z = fmaxf(o1.z, 0.f); o1.w = fmaxf(o1.w, 0.f);
        }
        *(float4*)&out[(size_t)node * 128 + f0] = o0;
        *(float4*)&out[(size_t)node * 128 + f0 + 4] = o1;
    }
}

extern "C" void kernel_launch(void* const* d_in, const int* in_sizes, int n_in,
                              void* d_out, int out_size, void* d_ws, size_t ws_size,
                              hipStream_t stream) {
    const float* x   = (const float*)d_in[0];
    const int*   ei  = (const int*)d_in[1];
    const float* W1  = (const float*)d_in[2];
    const float* a1s = (const float*)d_in[3];
    const float* a1d = (const float*)d_in[4];
    const float* b1  = (const float*)d_in[5];
    const float* W2  = (const float*)d_in[6];
    const float* a2s = (const float*)d_in[7];
    const float* a2d = (const float*)d_in[8];
    const float* b2  = (const float*)d_in[9];
    float* dout = (float*)d_out;

    const int n = in_sizes[0] / FD;          // 50000
    const int E = in_sizes[1] / 2;           // 1600000
    const int* src = ei;
    const int* dst = ei + E;
    const int NB = (n + CBW - 1) / CBW;      // 782 coarse buckets

    // workspace layout (ebuf aliases H: H is dead during CSR build)
    __half* H     = (__half*)d_ws;           // n*128 halves (12.8 MB)
    int*    ebuf  = (int*)d_ws;              // E ints (6.4 MB) — aliases H
    float* as_    = (float*)((char*)d_ws + (size_t)n * FD * sizeof(__half));
    float* ad_    = as_ + n;
    int*   rowptr = (int*)(ad_ + n);         // n+1
    int*   ccnt   = rowptr + (n + 1);        // NB
    int*   cbase  = ccnt + NB;               // NB+1
    int*   ccur   = cbase + NB + 1;          // NB
    int*   colidx = ccur + NB;               // E

    // ---- CSR build (shared by both layers) ----
    hipMemsetAsync(ccnt, 0, (size_t)NB * sizeof(int), stream);
    k_chist<<<256, 256, 0, stream>>>(dst, ccnt, E, NB);
    k_cscan<<<1, 1024, 0, stream>>>(ccnt, cbase, ccur, NB, rowptr, n);
    const int SCAT_BLOCKS = 256;
    k_cscatter<<<SCAT_BLOCKS, 256, 0, stream>>>(src, dst, ccur, ebuf, E, NB, SCAT_BLOCKS);
    k_fine<<<NB, 256, 0, stream>>>(ebuf, cbase, rowptr, colidx, n);

    const int gemm_grid = (n + BM - 1) / BM;
    const int node_grid = (n + 3) / 4;

    // ---- layer 1: h1 = x@W1 (+dots) -> aggregate -> relu -> d_out ----
    k_gemm<<<gemm_grid, 256, 0, stream>>>(x, W1, a1s, a1d, H, as_, ad_, n);
    k_aggr<<<node_grid, 256, 0, stream>>>(H, as_, ad_, rowptr, colidx, b1, dout, n, 1);

    // ---- layer 2: h2 = out1@W2 (+dots) -> aggregate -> d_out ----
    k_gemm<<<gemm_grid, 256, 0, stream>>>(dout, W2, a2s, a2d, H, as_, ad_, n);
    k_aggr<<<node_grid, 256, 0, stream>>>(H, as_, ad_, rowptr, colidx, b2, dout, n, 0);
}

// Round 4
// 254.730 us; speedup vs baseline: 2.4617x; 1.4039x over previous
//
#include <hip/hip_runtime.h>
#include <hip/hip_bf16.h>
#include <hip/hip_fp16.h>

#define FD 128
#define CBW 64            // coarse bucket width: bucket = dst >> 6
#define NB_MAX 1024

typedef _Float16 half8 __attribute__((ext_vector_type(8)));
typedef float f32x4 __attribute__((ext_vector_type(4)));

// ---------------- coarse histogram (LDS-aggregated) ----------------
__global__ __launch_bounds__(256) void k_chist(const int* __restrict__ dst,
                                               int* __restrict__ ccnt, int e, int nb) {
    __shared__ int lh[NB_MAX];
    for (int i = threadIdx.x; i < nb; i += 256) lh[i] = 0;
    __syncthreads();
    for (int i = blockIdx.x * 256 + threadIdx.x; i < e; i += gridDim.x * 256)
        atomicAdd(&lh[dst[i] >> 6], 1);
    __syncthreads();
    for (int i = threadIdx.x; i < nb; i += 256) {
        int c = lh[i];
        if (c) atomicAdd(&ccnt[i], c);
    }
}

// ---------------- scan of coarse counts (single block) ----------------
__global__ void k_cscan(const int* __restrict__ ccnt, int* __restrict__ cbase,
                        int* __restrict__ ccur, int nb, int* __restrict__ rowptr, int n) {
    __shared__ int wsum[16];
    __shared__ int woff[17];
    const int t = threadIdx.x, lane = t & 63, wid = t >> 6;
    int carry = 0;
    for (int base = 0; base < nb; base += 1024) {
        int idx = base + t;
        int v = (idx < nb) ? ccnt[idx] : 0;
        int s = v;
#pragma unroll
        for (int off = 1; off < 64; off <<= 1) {
            int u = __shfl_up(s, off, 64);
            if (lane >= off) s += u;
        }
        if (lane == 63) wsum[wid] = s;
        __syncthreads();
        if (wid == 0) {
            int w2 = (lane < 16) ? wsum[lane] : 0;
#pragma unroll
            for (int off = 1; off < 16; off <<= 1) {
                int u = __shfl_up(w2, off, 64);
                if (lane >= off) w2 += u;
            }
            if (lane < 16) woff[lane + 1] = w2;
            if (lane == 0) woff[0] = 0;
        }
        __syncthreads();
        int excl = carry + woff[wid] + (s - v);
        if (idx < nb) { cbase[idx] = excl; ccur[idx] = excl; }
        carry += woff[16];
        __syncthreads();
    }
    if (t == 0) { cbase[nb] = carry; rowptr[n] = carry; }
}

// ---------------- coarse scatter: pack (src<<6 | dst&63) into bucket-major ebuf ----------------
__global__ __launch_bounds__(256) void k_cscatter(const int* __restrict__ src,
                                                  const int* __restrict__ dst,
                                                  int* __restrict__ ccur,
                                                  int* __restrict__ ebuf,
                                                  int e, int nb, int nblocks) {
    __shared__ int lh[NB_MAX];
    __shared__ int lb[NB_MAX];
    const int per = (e + nblocks - 1) / nblocks;
    const int lo = blockIdx.x * per;
    const int hi = min(e, lo + per);
    const int t = threadIdx.x;
    for (int i = t; i < nb; i += 256) lh[i] = 0;
    __syncthreads();
    for (int i = lo + t; i < hi; i += 256) atomicAdd(&lh[dst[i] >> 6], 1);
    __syncthreads();
    for (int i = t; i < nb; i += 256) {
        int c = lh[i];
        lb[i] = c ? atomicAdd(&ccur[i], c) : 0;
    }
    __syncthreads();
    for (int i = t; i < nb; i += 256) lh[i] = 0;
    __syncthreads();
    for (int i = lo + t; i < hi; i += 256) {
        int d = dst[i];
        int bkt = d >> 6;
        int r = atomicAdd(&lh[bkt], 1);
        ebuf[lb[bkt] + r] = (src[i] << 6) | (d & (CBW - 1));
    }
}

// ---------------- fine counting sort within each coarse bucket ----------------
__global__ __launch_bounds__(256) void k_fine(const int* __restrict__ ebuf,
                                              const int* __restrict__ cbase,
                                              int* __restrict__ rowptr,
                                              int* __restrict__ colidx, int n) {
    const int b = blockIdx.x;
    const int node0 = b * CBW;
    const int nloc = min(CBW, n - node0);
    const int beg = cbase[b], end = cbase[b + 1];
    __shared__ int fh[CBW];
    __shared__ int fo[CBW];
    const int t = threadIdx.x;
    if (t < CBW) fh[t] = 0;
    __syncthreads();
    for (int e = beg + t; e < end; e += 256) atomicAdd(&fh[ebuf[e] & (CBW - 1)], 1);
    __syncthreads();
    if (t < 64) {
        int v = fh[t];
        int s = v;
#pragma unroll
        for (int off = 1; off < 64; off <<= 1) {
            int u = __shfl_up(s, off, 64);
            if (t >= off) s += u;
        }
        fo[t] = s - v;
    }
    __syncthreads();
    if (t < nloc) rowptr[node0 + t] = beg + fo[t];
    if (t < CBW) fh[t] = 0;
    __syncthreads();
    for (int e = beg + t; e < end; e += 256) {
        int v = ebuf[e];
        int d = v & (CBW - 1);
        int r = atomicAdd(&fh[d], 1);
        colidx[beg + fo[d] + r] = v >> 6;
    }
}

// ---------------- W -> W^T fp16 (blockIdx picks which matrix) ----------------
__global__ __launch_bounds__(1024) void k_wt(const float* __restrict__ Wa,
                                             const float* __restrict__ Wb,
                                             __half* __restrict__ Ta,
                                             __half* __restrict__ Tb) {
    __shared__ float sw[128 * 129];
    const float* W = blockIdx.x ? Wb : Wa;
    __half* T = blockIdx.x ? Tb : Ta;
    const int t = threadIdx.x;
#pragma unroll
    for (int i = 0; i < 16; i++) {
        int idx = i * 1024 + t;
        sw[(idx >> 7) * 129 + (idx & 127)] = W[idx];
    }
    __syncthreads();
#pragma unroll
    for (int i = 0; i < 8; i++) {
        int o = i * 1024 + t;       // half2-pair index
        int c = o >> 6, kp = o & 63;
        float lo = sw[(kp * 2) * 129 + c];
        float hi = sw[(kp * 2 + 1) * 129 + c];
        *(__half2*)&T[c * 128 + kp * 2] = __floats2half2_rn(lo, hi);
    }
}

// ---------------- MFMA GEMM: H = X @ W (fp16 in, fp32 acc) + fused dots ----------------
// No LDS. A-frags straight from row-major X; B-frags from 32KB L1-resident Wt (=W^T, [col][k]).
// A/B use identical (group,elem)->k packing (slot-symmetric => any consistent bijection is exact).
__global__ __launch_bounds__(256) void k_gemm(const float* __restrict__ X,
                                              const __half* __restrict__ Wt,
                                              const float* __restrict__ a_s,
                                              const float* __restrict__ a_d,
                                              __half* __restrict__ H,
                                              float* __restrict__ as_,
                                              float* __restrict__ ad_, int n) {
    const int t = threadIdx.x;
    const int wave = t >> 6, lane = t & 63;
    const int g = lane >> 4, c16 = lane & 15;
    const int row0 = blockIdx.x * 64 + wave * 16;

    // A fragments: row = row0 + c16, k = kc*32 + g*8 + e
    half8 A[4];
    {
        int row = row0 + c16;
        int rc = (row < n) ? row : (n - 1);
        const float* xp = &X[(size_t)rc * 128 + g * 8];
#pragma unroll
        for (int kc = 0; kc < 4; kc++) {
            float4 x0 = *(const float4*)(xp + kc * 32);
            float4 x1 = *(const float4*)(xp + kc * 32 + 4);
            half8 a;
            a[0] = (_Float16)x0.x; a[1] = (_Float16)x0.y;
            a[2] = (_Float16)x0.z; a[3] = (_Float16)x0.w;
            a[4] = (_Float16)x1.x; a[5] = (_Float16)x1.y;
            a[6] = (_Float16)x1.z; a[7] = (_Float16)x1.w;
            A[kc] = a;
        }
    }

    f32x4 acc[8];
#pragma unroll
    for (int ct = 0; ct < 8; ct++) acc[ct] = (f32x4){0.f, 0.f, 0.f, 0.f};

#pragma unroll
    for (int ct = 0; ct < 8; ct++) {
        const __half* wp = &Wt[(ct * 16 + c16) * 128 + g * 8];
#pragma unroll
        for (int kc = 0; kc < 4; kc++) {
            half8 b = *(const half8*)(wp + kc * 32);
            acc[ct] = __builtin_amdgcn_mfma_f32_16x16x32_f16(A[kc], b, acc[ct], 0, 0, 0);
        }
    }

    // epilogue: H fp16 + attention dots. C/D: col = ct*16 + c16, row = row0 + g*4 + r
    float asv[8], adv[8];
#pragma unroll
    for (int ct = 0; ct < 8; ct++) {
        asv[ct] = a_s[ct * 16 + c16];
        adv[ct] = a_d[ct * 16 + c16];
    }
#pragma unroll
    for (int r = 0; r < 4; r++) {
        const int row = row0 + g * 4 + r;
        float vs = 0.f, vd = 0.f;
#pragma unroll
        for (int ct = 0; ct < 8; ct++) {
            float v = acc[ct][r];
            vs += v * asv[ct];
            vd += v * adv[ct];
            if (row < n) H[(size_t)row * 128 + ct * 16 + c16] = __float2half(v);
        }
#pragma unroll
        for (int off = 8; off; off >>= 1) {
            vs += __shfl_xor(vs, off, 16);
            vd += __shfl_xor(vd, off, 16);
        }
        if (c16 == 0 && row < n) { as_[row] = vs; ad_[row] = vd; }
    }
}

// ---------------- fused softmax + aggregation: 1 wave/node, 4 edges in flight ----------------
__global__ __launch_bounds__(256) void k_aggr(const __half* __restrict__ H,
                                              const float* __restrict__ as_,
                                              const float* __restrict__ ad_,
                                              const int* __restrict__ rowptr,
                                              const int* __restrict__ colidx,
                                              const float* __restrict__ bias,
                                              float* __restrict__ out, int n, int do_relu) {
    const int wid = threadIdx.x >> 6;
    const int lane = threadIdx.x & 63;
    const int node = blockIdx.x * 4 + wid;
    if (node >= n) return;
    const int q = lane >> 4;
    const int l = lane & 15;
    const int f0 = l * 8;
    const float adn = ad_[node];
    float s_acc = 0.f;
    float a0 = 0.f, a1 = 0.f, a2 = 0.f, a3 = 0.f, a4 = 0.f, a5 = 0.f, a6 = 0.f, a7 = 0.f;
    const int beg = rowptr[node], end = rowptr[node + 1];
    int i = beg + q;
    int src_n = 0; float as_n = 0.f;
    if (i < end) { src_n = colidx[i]; as_n = as_[src_n]; }
    while (i < end) {
        const int src_c = src_n; const float as_c = as_n;
        const uint4 hv = *(const uint4*)&H[(size_t)src_c * 128 + f0];
        const int i2 = i + 4;
        if (i2 < end) { src_n = colidx[i2]; as_n = as_[src_n]; }
        float e = as_c + adn;
        e = (e > 0.f) ? e : 0.2f * e;
        const float w = __expf(e);
        s_acc += w;
        float2 p;
        p = __half22float2(*(const __half2*)&hv.x); a0 += w * p.x; a1 += w * p.y;
        p = __half22float2(*(const __half2*)&hv.y); a2 += w * p.x; a3 += w * p.y;
        p = __half22float2(*(const __half2*)&hv.z); a4 += w * p.x; a5 += w * p.y;
        p = __half22float2(*(const __half2*)&hv.w); a6 += w * p.x; a7 += w * p.y;
        i = i2;
    }
    if (q == 3) {   // self loop
        float e = as_[node] + adn;
        e = (e > 0.f) ? e : 0.2f * e;
        const float w = __expf(e);
        s_acc += w;
        const uint4 hv = *(const uint4*)&H[(size_t)node * 128 + f0];
        float2 p;
        p = __half22float2(*(const __half2*)&hv.x); a0 += w * p.x; a1 += w * p.y;
        p = __half22float2(*(const __half2*)&hv.y); a2 += w * p.x; a3 += w * p.y;
        p = __half22float2(*(const __half2*)&hv.z); a4 += w * p.x; a5 += w * p.y;
        p = __half22float2(*(const __half2*)&hv.w); a6 += w * p.x; a7 += w * p.y;
    }
#pragma unroll
    for (int off = 16; off <= 32; off <<= 1) {
        s_acc += __shfl_xor(s_acc, off);
        a0 += __shfl_xor(a0, off); a1 += __shfl_xor(a1, off);
        a2 += __shfl_xor(a2, off); a3 += __shfl_xor(a3, off);
        a4 += __shfl_xor(a4, off); a5 += __shfl_xor(a5, off);
        a6 += __shfl_xor(a6, off); a7 += __shfl_xor(a7, off);
    }
    if (q == 0) {
        const float inv = 1.f / s_acc;
        const float4 b0 = *(const float4*)&bias[f0];
        const float4 b1 = *(const float4*)&bias[f0 + 4];
        float4 o0, o1;
        o0.x = a0 * inv + b0.x; o0.y = a1 * inv + b0.y;
        o0.z = a2 * inv + b0.z; o0.w = a3 * inv + b0.w;
        o1.x = a4 * inv + b1.x; o1.y = a5 * inv + b1.y;
        o1.z = a6 * inv + b1.z; o1.w = a7 * inv + b1.w;
        if (do_relu) {
            o0.x = fmaxf(o0.x, 0.f); o0.y = fmaxf(o0.y, 0.f);
            o0.z = fmaxf(o0.z, 0.f); o0.w = fmaxf(o0.w, 0.f);
            o1.x = fmaxf(o1.x, 0.f); o1.y = fmaxf(o1.y, 0.f);
            o1.z = fmaxf(o1.z, 0.f); o1.w = fmaxf(o1.w, 0.f);
        }
        *(float4*)&out[(size_t)node * 128 + f0] = o0;
        *(float4*)&out[(size_t)node * 128 + f0 + 4] = o1;
    }
}

extern "C" void kernel_launch(void* const* d_in, const int* in_sizes, int n_in,
                              void* d_out, int out_size, void* d_ws, size_t ws_size,
                              hipStream_t stream) {
    const float* x   = (const float*)d_in[0];
    const int*   ei  = (const int*)d_in[1];
    const float* W1  = (const float*)d_in[2];
    const float* a1s = (const float*)d_in[3];
    const float* a1d = (const float*)d_in[4];
    const float* b1  = (const float*)d_in[5];
    const float* W2  = (const float*)d_in[6];
    const float* a2s = (const float*)d_in[7];
    const float* a2d = (const float*)d_in[8];
    const float* b2  = (const float*)d_in[9];
    float* dout = (float*)d_out;

    const int n = in_sizes[0] / FD;          // 50000
    const int E = in_sizes[1] / 2;           // 1600000
    const int* src = ei;
    const int* dst = ei + E;
    const int NB = (n + CBW - 1) / CBW;      // 782 coarse buckets

    // workspace layout (ebuf aliases H: H is dead during CSR build)
    __half* H     = (__half*)d_ws;           // n*128 halves (12.8 MB)
    int*    ebuf  = (int*)d_ws;              // E ints (6.4 MB) — aliases H
    float* as_    = (float*)((char*)d_ws + (size_t)n * FD * sizeof(__half));
    float* ad_    = as_ + n;
    int*   rowptr = (int*)(ad_ + n);         // n+1
    int*   ccnt   = rowptr + (n + 1);        // NB
    int*   cbase  = ccnt + NB;               // NB+1
    int*   ccur   = cbase + NB + 1;          // NB
    int*   colidx = ccur + NB;               // E
    // 16B-aligned fp16 transposed weights after colidx
    size_t wt_off = (((size_t)((char*)(colidx + E) - (char*)d_ws)) + 15) & ~(size_t)15;
    __half* Wt1h  = (__half*)((char*)d_ws + wt_off);          // 32 KB
    __half* Wt2h  = Wt1h + 128 * 128;                          // 32 KB

    // ---- weight transpose + CSR build (shared by both layers) ----
    k_wt<<<2, 1024, 0, stream>>>(W1, W2, Wt1h, Wt2h);
    hipMemsetAsync(ccnt, 0, (size_t)NB * sizeof(int), stream);
    k_chist<<<256, 256, 0, stream>>>(dst, ccnt, E, NB);
    k_cscan<<<1, 1024, 0, stream>>>(ccnt, cbase, ccur, NB, rowptr, n);
    const int SCAT_BLOCKS = 256;
    k_cscatter<<<SCAT_BLOCKS, 256, 0, stream>>>(src, dst, ccur, ebuf, E, NB, SCAT_BLOCKS);
    k_fine<<<NB, 256, 0, stream>>>(ebuf, cbase, rowptr, colidx, n);

    const int gemm_grid = (n + 63) / 64;
    const int node_grid = (n + 3) / 4;

    // ---- layer 1 ----
    k_gemm<<<gemm_grid, 256, 0, stream>>>(x, Wt1h, a1s, a1d, H, as_, ad_, n);
    k_aggr<<<node_grid, 256, 0, stream>>>(H, as_, ad_, rowptr, colidx, b1, dout, n, 1);

    // ---- layer 2 ----
    k_gemm<<<gemm_grid, 256, 0, stream>>>(dout, Wt2h, a2s, a2d, H, as_, ad_, n);
    k_aggr<<<node_grid, 256, 0, stream>>>(H, as_, ad_, rowptr, colidx, b2, dout, n, 0);
}